// Round 3
// baseline (200.748 us; speedup 1.0000x reference)
//
#include <hip/hip_runtime.h>
#include <hip/hip_bf16.h>

#define LQ 2048
#define LKV 2048
#define DM 512
#define NH 8
#define DK 64

typedef __attribute__((ext_vector_type(8))) __bf16 bf16x8;
typedef __attribute__((ext_vector_type(4))) float f32x4;
typedef __attribute__((ext_vector_type(16))) float f32x16;

static __device__ __forceinline__ unsigned short f2bf(float x) {
  unsigned u = __float_as_uint(x);
  return (unsigned short)((u + 0x7fffu + ((u >> 16) & 1u)) >> 16);
}
static __device__ __forceinline__ float bf2f(unsigned short u) {
  return __uint_as_float(((unsigned)u) << 16);
}

// ---------------------------------------------------------------------------
// Transpose+convert W[512][512] f32 -> Wt[512][512] bf16 (Wt[n][k] = W[k][n])
// ---------------------------------------------------------------------------
__global__ __launch_bounds__(256) void transpose_w(
    const float* __restrict__ Wq, const float* __restrict__ Wk,
    const float* __restrict__ Wv, const float* __restrict__ Wo,
    unsigned short* __restrict__ WtAll)
{
  const float* W = blockIdx.z == 0 ? Wq : blockIdx.z == 1 ? Wk : blockIdx.z == 2 ? Wv : Wo;
  unsigned short* Wt = WtAll + (size_t)blockIdx.z * DM * DM;
  __shared__ float tile[32][33];
  const int t = threadIdx.x;
  const int tr = t >> 3;
  const int tc4 = (t & 7) * 4;
  const int k0 = blockIdx.x * 32, n0 = blockIdx.y * 32;
  float4 v = *(const float4*)(W + (size_t)(k0 + tr) * DM + n0 + tc4);
  tile[tr][tc4 + 0] = v.x; tile[tr][tc4 + 1] = v.y;
  tile[tr][tc4 + 2] = v.z; tile[tr][tc4 + 3] = v.w;
  __syncthreads();
  ushort4 o;
  o.x = f2bf(tile[tc4 + 0][tr]);
  o.y = f2bf(tile[tc4 + 1][tr]);
  o.z = f2bf(tile[tc4 + 2][tr]);
  o.w = f2bf(tile[tc4 + 3][tr]);
  *(ushort4*)(Wt + (size_t)(n0 + tr) * DM + k0 + tc4) = o;
}

// ---------------------------------------------------------------------------
// QKV projection GEMM -> head-major bf16 [B,H,L,64]; q scaled by log2e/8
// ---------------------------------------------------------------------------
__global__ __launch_bounds__(256) void gemm_qkv(
    const float* __restrict__ qin, const float* __restrict__ kin, const float* __restrict__ vin,
    const unsigned short* __restrict__ WtAll,
    const float* __restrict__ bq, const float* __restrict__ bk, const float* __restrict__ bv,
    unsigned short* __restrict__ qh, unsigned short* __restrict__ kh, unsigned short* __restrict__ vh)
{
  const int mode = blockIdx.z;
  const float* A = mode == 0 ? qin : (mode == 1 ? kin : vin);
  const unsigned short* Bt = WtAll + (size_t)mode * DM * DM;
  const float* bias = mode == 0 ? bq : (mode == 1 ? bk : bv);
  unsigned short* out = mode == 0 ? qh : (mode == 1 ? kh : vh);
  const float scale = (mode == 0) ? 0.18033688011112042f : 1.0f; // log2(e)/8

  __shared__ __align__(16) unsigned short Al[128 * 40];
  __shared__ __align__(16) unsigned short Bl[128 * 40];

  const int tid = threadIdx.x;
  const int lane = tid & 63;
  const int w = tid >> 6;
  const int wr = w >> 1, wc = w & 1;
  const int l15 = lane & 15, g = lane >> 4;
  const int m0 = blockIdx.x * 128, n0 = blockIdx.y * 128;

  f32x4 acc[4][4] = {};

  for (int k0 = 0; k0 < DM; k0 += 32) {
#pragma unroll
    for (int i = 0; i < 4; ++i) {
      int idx = tid + i * 256;
      int row = idx >> 3, seg = idx & 7;
      float4 v = *(const float4*)(A + (size_t)(m0 + row) * DM + k0 + seg * 4);
      ushort4 pk;
      pk.x = f2bf(v.x); pk.y = f2bf(v.y); pk.z = f2bf(v.z); pk.w = f2bf(v.w);
      *(ushort4*)(&Al[row * 40 + seg * 4]) = pk;
    }
#pragma unroll
    for (int i = 0; i < 2; ++i) {
      int idx = tid + i * 256;
      int row = idx >> 2, seg = idx & 3;
      *(int4*)(&Bl[row * 40 + seg * 8]) =
          *(const int4*)(Bt + (size_t)(n0 + row) * DM + k0 + seg * 8);
    }
    __syncthreads();
    bf16x8 af[4], bfr[4];
#pragma unroll
    for (int mi = 0; mi < 4; ++mi)
      af[mi] = *(const bf16x8*)(&Al[(wr * 64 + mi * 16 + l15) * 40 + g * 8]);
#pragma unroll
    for (int ni = 0; ni < 4; ++ni)
      bfr[ni] = *(const bf16x8*)(&Bl[(wc * 64 + ni * 16 + l15) * 40 + g * 8]);
#pragma unroll
    for (int mi = 0; mi < 4; ++mi)
#pragma unroll
      for (int ni = 0; ni < 4; ++ni)
        acc[mi][ni] = __builtin_amdgcn_mfma_f32_16x16x32_bf16(af[mi], bfr[ni], acc[mi][ni], 0, 0, 0);
    __syncthreads();
  }

#pragma unroll
  for (int mi = 0; mi < 4; ++mi) {
#pragma unroll
    for (int ni = 0; ni < 4; ++ni) {
      int n = n0 + wc * 64 + ni * 16 + l15;
      float bs = bias[n];
      int h = n >> 6, d = n & 63;
#pragma unroll
      for (int r = 0; r < 4; ++r) {
        int m = m0 + wr * 64 + mi * 16 + g * 4 + r;
        int b = m >> 11, li = m & 2047;
        float val = (acc[mi][ni][r] + bs) * scale;
        out[(((size_t)(b * NH + h)) * LQ + li) * DK + d] = f2bf(val);
      }
    }
  }
}

// ---------------------------------------------------------------------------
// Output GEMM: A[8192][512] bf16 @ Wo^T + bo -> f32
// ---------------------------------------------------------------------------
__global__ __launch_bounds__(256) void gemm_out(
    const unsigned short* __restrict__ A, const unsigned short* __restrict__ Bt,
    const float* __restrict__ bias, float* __restrict__ out)
{
  __shared__ __align__(16) unsigned short Al[128 * 40];
  __shared__ __align__(16) unsigned short Bl[128 * 40];
  const int tid = threadIdx.x;
  const int lane = tid & 63;
  const int w = tid >> 6;
  const int wr = w >> 1, wc = w & 1;
  const int l15 = lane & 15, g = lane >> 4;
  const int m0 = blockIdx.x * 128, n0 = blockIdx.y * 128;
  f32x4 acc[4][4] = {};

  for (int k0 = 0; k0 < DM; k0 += 32) {
#pragma unroll
    for (int i = 0; i < 2; ++i) {
      int idx = tid + i * 256;
      int row = idx >> 2, seg = idx & 3;
      *(int4*)(&Al[row * 40 + seg * 8]) =
          *(const int4*)(A + (size_t)(m0 + row) * DM + k0 + seg * 8);
      *(int4*)(&Bl[row * 40 + seg * 8]) =
          *(const int4*)(Bt + (size_t)(n0 + row) * DM + k0 + seg * 8);
    }
    __syncthreads();
    bf16x8 af[4], bfr[4];
#pragma unroll
    for (int mi = 0; mi < 4; ++mi)
      af[mi] = *(const bf16x8*)(&Al[(wr * 64 + mi * 16 + l15) * 40 + g * 8]);
#pragma unroll
    for (int ni = 0; ni < 4; ++ni)
      bfr[ni] = *(const bf16x8*)(&Bl[(wc * 64 + ni * 16 + l15) * 40 + g * 8]);
#pragma unroll
    for (int mi = 0; mi < 4; ++mi)
#pragma unroll
      for (int ni = 0; ni < 4; ++ni)
        acc[mi][ni] = __builtin_amdgcn_mfma_f32_16x16x32_bf16(af[mi], bfr[ni], acc[mi][ni], 0, 0, 0);
    __syncthreads();
  }

#pragma unroll
  for (int mi = 0; mi < 4; ++mi) {
#pragma unroll
    for (int ni = 0; ni < 4; ++ni) {
      int n = n0 + wc * 64 + ni * 16 + l15;
      float bs = bias[n];
#pragma unroll
      for (int r = 0; r < 4; ++r) {
        int m = m0 + wr * 64 + mi * 16 + g * 4 + r;
        out[(size_t)m * DM + n] = acc[mi][ni][r] + bs;
      }
    }
  }
}

// ---------------------------------------------------------------------------
// V transpose with weight fold: vh[b,h,l,d] -> vt[b,h,d,l] = w[l]*v
// also emits wbf[b][l] = bf16(w[l]) (once per b, gated on h==0)
// ---------------------------------------------------------------------------
__global__ __launch_bounds__(256) void transpose_v(
    const unsigned short* __restrict__ vh, const float* __restrict__ wts,
    unsigned short* __restrict__ vt, unsigned short* __restrict__ wbf)
{
  __shared__ __align__(16) unsigned short t[64 * 72];
  const int bh = blockIdx.y, l0 = blockIdx.x * 64;
  const int b = bh >> 3;
  const size_t base = (size_t)bh * LKV * DK;
  const int tid = threadIdx.x;
  if ((bh & 7) == 0 && tid < 64)
    wbf[b * LKV + l0 + tid] = f2bf(wts[b * LKV + l0 + tid]);
#pragma unroll
  for (int i = 0; i < 2; ++i) {
    int idx = tid + i * 256;
    int row = idx >> 3, seg = idx & 7;
    *(int4*)(&t[row * 72 + seg * 8]) =
        *(const int4*)(vh + base + (size_t)(l0 + row) * DK + seg * 8);
  }
  __syncthreads();
#pragma unroll
  for (int i = 0; i < 2; ++i) {
    int idx = tid + i * 256;
    int d = idx >> 3, seg = idx & 7;
    int kvg = l0 + seg * 8;
    float4 wa = *(const float4*)(wts + b * LKV + kvg);
    float4 wb = *(const float4*)(wts + b * LKV + kvg + 4);
    unsigned short r0 = f2bf(wa.x * bf2f(t[(seg * 8 + 0) * 72 + d]));
    unsigned short r1 = f2bf(wa.y * bf2f(t[(seg * 8 + 1) * 72 + d]));
    unsigned short r2 = f2bf(wa.z * bf2f(t[(seg * 8 + 2) * 72 + d]));
    unsigned short r3 = f2bf(wa.w * bf2f(t[(seg * 8 + 3) * 72 + d]));
    unsigned short r4 = f2bf(wb.x * bf2f(t[(seg * 8 + 4) * 72 + d]));
    unsigned short r5 = f2bf(wb.y * bf2f(t[(seg * 8 + 5) * 72 + d]));
    unsigned short r6 = f2bf(wb.z * bf2f(t[(seg * 8 + 6) * 72 + d]));
    unsigned short r7 = f2bf(wb.w * bf2f(t[(seg * 8 + 7) * 72 + d]));
    int4 o;
    o.x = (int)((unsigned)r0 | ((unsigned)r1 << 16));
    o.y = (int)((unsigned)r2 | ((unsigned)r3 << 16));
    o.z = (int)((unsigned)r4 | ((unsigned)r5 << 16));
    o.w = (int)((unsigned)r6 | ((unsigned)r7 << 16));
    *(int4*)(vt + base + (size_t)d * LKV + l0 + seg * 8) = o;
  }
}

// ---------------------------------------------------------------------------
// Flash attention, swapped-QK 32x32 MFMA, no-max softmax, w folded into V.
// KV-split x4 within block: 4 waves each own 512 kv of the SAME 32 q rows;
// partials combined additively in LDS (valid because no-max softmax partials
// are pure sums). K/V/w read DIRECT from L2 (no staging, no loop barriers).
// grid 2048 = 32 bh (XCD-grouped) x 64 q-blocks, block 256.
// ---------------------------------------------------------------------------
__global__ __launch_bounds__(256, 4) void attn_fwd(
    const unsigned short* __restrict__ qh, const unsigned short* __restrict__ kh,
    const unsigned short* __restrict__ vt, const unsigned short* __restrict__ wbf,
    unsigned short* __restrict__ ao)
{
  const int bid = blockIdx.x;
  const int xcd = bid & 7, wi = bid >> 3;       // 2048 blocks, 256 per XCD
  const int bh = xcd * 4 + (wi >> 6);           // 4 bh per XCD -> K/V L2-resident
  const int qb = wi & 63;
  const int b = bh >> 3, h = bh & 7;
  const int tid = threadIdx.x, lane = tid & 63, w = tid >> 6;
  const int l31 = lane & 31, hi = lane >> 5;

  __shared__ __align__(16) float Ob[4][32][68];
  __shared__ float Lb[4][32];

  const size_t basebh = (size_t)bh * LKV * DK;
  const int q0 = qb * 32;

  // Q B-fragments: col q = q0 + l31, k-chunk d = cq*16 + hi*8 + j
  bf16x8 qf[4];
  {
    const unsigned short* qp = qh + basebh + (size_t)(q0 + l31) * DK + hi * 8;
#pragma unroll
    for (int cq = 0; cq < 4; ++cq) qf[cq] = *(const bf16x8*)(qp + cq * 16);
  }

  f32x16 accO0 = {}, accO1 = {}, accL = {};

  const unsigned short* Kbase = kh + basebh + (size_t)l31 * DK + hi * 8;
  const unsigned short* Vbase = vt + basebh + (size_t)l31 * LKV + hi * 8;
  const unsigned short* Wbase = wbf + b * LKV + hi * 8;

#pragma unroll 2
  for (int t = 0; t < 8; ++t) {
    const int kv0 = w * 512 + t * 64;

    // ---- S^T = K·Q^T: lane l31 = q, kv = (r&3)+8*(r>>2)+4*hi+32*half ----
    f32x16 S[2];
#pragma unroll
    for (int half = 0; half < 2; ++half) {
      f32x16 s = {};
#pragma unroll
      for (int cq = 0; cq < 4; ++cq) {
        bf16x8 kf = *(const bf16x8*)(Kbase + (size_t)(kv0 + half * 32) * DK + cq * 16);
        s = __builtin_amdgcn_mfma_f32_32x32x16_bf16(kf, qf[cq], s, 0, 0, 0);
      }
      S[half] = s;
    }

    // ---- u = exp2(S) (scale pre-folded into qh), pack bf16 pairs ----
    unsigned D[16];
#pragma unroll
    for (int half = 0; half < 2; ++half) {
#pragma unroll
      for (int r2 = 0; r2 < 8; ++r2) {
        float lo = __builtin_amdgcn_exp2f(S[half][2 * r2]);
        float hv = __builtin_amdgcn_exp2f(S[half][2 * r2 + 1]);
        __bf16 bl = (__bf16)lo, bh2 = (__bf16)hv;
        unsigned short ul = __builtin_bit_cast(unsigned short, bl);
        unsigned short uh = __builtin_bit_cast(unsigned short, bh2);
        D[half * 8 + r2] = (unsigned)ul | ((unsigned)uh << 16);
      }
    }

    // ---- exchange to PV A-frag + MFMA PV and denominator ----
#pragma unroll
    for (int c = 0; c < 4; ++c) {
      int base = 4 * (c & 1) + 8 * (c >> 1);
      unsigned s0 = hi ? D[base] : D[base + 2];
      unsigned s1 = hi ? D[base + 1] : D[base + 3];
      unsigned X0 = (unsigned)__shfl_xor((int)s0, 32);
      unsigned X1 = (unsigned)__shfl_xor((int)s1, 32);
      union { unsigned u[4]; bf16x8 v; } pa;
      pa.u[0] = hi ? X0 : D[base];
      pa.u[1] = hi ? X1 : D[base + 1];
      pa.u[2] = hi ? D[base + 2] : X0;
      pa.u[3] = hi ? D[base + 3] : X1;

      const unsigned short* vp = Vbase + kv0 + c * 16;
      bf16x8 vb0 = *(const bf16x8*)(vp);
      bf16x8 vb1 = *(const bf16x8*)(vp + 32 * LKV);
      bf16x8 wb = {};
      if (l31 == 0) wb = *(const bf16x8*)(Wbase + kv0 + c * 16);

      accO0 = __builtin_amdgcn_mfma_f32_32x32x16_bf16(pa.v, vb0, accO0, 0, 0, 0);
      accO1 = __builtin_amdgcn_mfma_f32_32x32x16_bf16(pa.v, vb1, accO1, 0, 0, 0);
      accL  = __builtin_amdgcn_mfma_f32_32x32x16_bf16(pa.v, wb,  accL,  0, 0, 0);
    }
  }

  // ---- write per-wave partials ----
#pragma unroll
  for (int r = 0; r < 16; ++r) {
    int q = (r & 3) + 8 * (r >> 2) + 4 * hi;
    Ob[w][q][l31] = accO0[r];
    Ob[w][q][32 + l31] = accO1[r];
  }
  if (l31 == 0) {
#pragma unroll
    for (int r = 0; r < 16; ++r) {
      int q = (r & 3) + 8 * (r >> 2) + 4 * hi;
      Lb[w][q] = accL[r];
    }
  }
  __syncthreads();

  // ---- combine 4 partials + normalize + store (thread t -> q=t>>3, 8 d) ----
  {
    int q = tid >> 3, oc = tid & 7;
    float L = Lb[0][q] + Lb[1][q] + Lb[2][q] + Lb[3][q];
    float inv = 1.0f / L;
    unsigned us[8];
#pragma unroll
    for (int j = 0; j < 8; ++j) {
      int d = oc * 8 + j;
      float s = Ob[0][q][d] + Ob[1][q][d] + Ob[2][q][d] + Ob[3][q][d];
      us[j] = (unsigned)f2bf(s * inv);
    }
    int4 o;
    o.x = (int)(us[0] | (us[1] << 16));
    o.y = (int)(us[2] | (us[3] << 16));
    o.z = (int)(us[4] | (us[5] << 16));
    o.w = (int)(us[6] | (us[7] << 16));
    size_t off = ((size_t)(b * LQ + q0 + q)) * DM + h * DK + oc * 8;
    *(int4*)(ao + off) = o;
  }
}

// ---------------------------------------------------------------------------
extern "C" void kernel_launch(void* const* d_in, const int* in_sizes, int n_in,
                              void* d_out, int out_size, void* d_ws, size_t ws_size,
                              hipStream_t stream)
{
  const float* q  = (const float*)d_in[0];
  const float* k  = (const float*)d_in[1];
  const float* v  = (const float*)d_in[2];
  const float* wt = (const float*)d_in[3];
  const float* Wq = (const float*)d_in[4];
  const float* bq = (const float*)d_in[5];
  const float* Wk = (const float*)d_in[6];
  const float* bk = (const float*)d_in[7];
  const float* Wv = (const float*)d_in[8];
  const float* bv = (const float*)d_in[9];
  const float* Wo = (const float*)d_in[10];
  const float* bo = (const float*)d_in[11];

  char* ws = (char*)d_ws;
  unsigned short* qh = (unsigned short*)(ws + 0);           //  8 MiB  [B,H,L,64] (scaled)
  unsigned short* kh = (unsigned short*)(ws + 8388608);     //  8 MiB  [B,H,L,64]
  unsigned short* vtr= (unsigned short*)(ws + 16777216);    //  8 MiB  [B,H,64,L] (w-scaled)
  unsigned short* ao = (unsigned short*)(ws + 25165824);    //  8 MiB  [B,L,512]
  unsigned short* Wt = (unsigned short*)(ws + 33554432);    //  2 MiB  4x[512][512]
  unsigned short* vh = (unsigned short*)(ws + 35651584);    //  8 MiB  [B,H,L,64]
  unsigned short* wbf= (unsigned short*)(ws + 44040192);    // 16 KiB  [B,LKV] bf16 w

  transpose_w<<<dim3(16, 16, 4), 256, 0, stream>>>(Wq, Wk, Wv, Wo, Wt);
  gemm_qkv<<<dim3(64, 4, 3), 256, 0, stream>>>(q, k, v, Wt, bq, bk, bv, qh, kh, vh);
  transpose_v<<<dim3(32, 32), 256, 0, stream>>>(vh, wt, vtr, wbf);
  attn_fwd<<<2048, 256, 0, stream>>>(qh, kh, vtr, wbf, ao);
  gemm_out<<<dim3(64, 4), 256, 0, stream>>>(ao, Wt + 3 * (size_t)DM * DM, bo, (float*)d_out);
}

// Round 4
// 113.103 us; speedup vs baseline: 1.7749x; 1.7749x over previous
//
#include <hip/hip_runtime.h>
#include <hip/hip_bf16.h>

#define LQ 2048
#define LKV 2048
#define DM 512
#define NH 8
#define DK 64

typedef __attribute__((ext_vector_type(8))) __bf16 bf16x8;
typedef __attribute__((ext_vector_type(4))) float f32x4;
typedef __attribute__((ext_vector_type(16))) float f32x16;

#define AS1 __attribute__((address_space(1)))
#define AS3 __attribute__((address_space(3)))

static __device__ __forceinline__ unsigned short f2bf(float x) {
  unsigned u = __float_as_uint(x);
  return (unsigned short)((u + 0x7fffu + ((u >> 16) & 1u)) >> 16);
}
static __device__ __forceinline__ float bf2f(unsigned short u) {
  return __uint_as_float(((unsigned)u) << 16);
}

// ---------------------------------------------------------------------------
// Transpose+convert W[512][512] f32 -> Wt[512][512] bf16 (Wt[n][k] = W[k][n])
// ---------------------------------------------------------------------------
__global__ __launch_bounds__(256) void transpose_w(
    const float* __restrict__ Wq, const float* __restrict__ Wk,
    const float* __restrict__ Wv, const float* __restrict__ Wo,
    unsigned short* __restrict__ WtAll)
{
  const float* W = blockIdx.z == 0 ? Wq : blockIdx.z == 1 ? Wk : blockIdx.z == 2 ? Wv : Wo;
  unsigned short* Wt = WtAll + (size_t)blockIdx.z * DM * DM;
  __shared__ float tile[32][33];
  const int t = threadIdx.x;
  const int tr = t >> 3;
  const int tc4 = (t & 7) * 4;
  const int k0 = blockIdx.x * 32, n0 = blockIdx.y * 32;
  float4 v = *(const float4*)(W + (size_t)(k0 + tr) * DM + n0 + tc4);
  tile[tr][tc4 + 0] = v.x; tile[tr][tc4 + 1] = v.y;
  tile[tr][tc4 + 2] = v.z; tile[tr][tc4 + 3] = v.w;
  __syncthreads();
  ushort4 o;
  o.x = f2bf(tile[tc4 + 0][tr]);
  o.y = f2bf(tile[tc4 + 1][tr]);
  o.z = f2bf(tile[tc4 + 2][tr]);
  o.w = f2bf(tile[tc4 + 3][tr]);
  *(ushort4*)(Wt + (size_t)(n0 + tr) * DM + k0 + tc4) = o;
}

// ---------------------------------------------------------------------------
// QKV projection GEMM. Q -> row-major head-major bf16 (scaled by log2e/8),
// K -> MFMA A-fragment layout kf[bh][t32][cq][lane][8], V -> row-major vh.
// ---------------------------------------------------------------------------
__global__ __launch_bounds__(256) void gemm_qkv(
    const float* __restrict__ qin, const float* __restrict__ kin, const float* __restrict__ vin,
    const unsigned short* __restrict__ WtAll,
    const float* __restrict__ bq, const float* __restrict__ bk, const float* __restrict__ bv,
    unsigned short* __restrict__ qh, unsigned short* __restrict__ kfo, unsigned short* __restrict__ vh)
{
  const int mode = blockIdx.z;
  const float* A = mode == 0 ? qin : (mode == 1 ? kin : vin);
  const unsigned short* Bt = WtAll + (size_t)mode * DM * DM;
  const float* bias = mode == 0 ? bq : (mode == 1 ? bk : bv);
  const float scale = (mode == 0) ? 0.18033688011112042f : 1.0f; // log2(e)/8

  __shared__ __align__(16) unsigned short Al[128 * 40];
  __shared__ __align__(16) unsigned short Bl[128 * 40];

  const int tid = threadIdx.x;
  const int lane = tid & 63;
  const int w = tid >> 6;
  const int wr = w >> 1, wc = w & 1;
  const int l15 = lane & 15, g = lane >> 4;
  const int m0 = blockIdx.x * 128, n0 = blockIdx.y * 128;

  f32x4 acc[4][4] = {};

  for (int k0 = 0; k0 < DM; k0 += 32) {
#pragma unroll
    for (int i = 0; i < 4; ++i) {
      int idx = tid + i * 256;
      int row = idx >> 3, seg = idx & 7;
      float4 v = *(const float4*)(A + (size_t)(m0 + row) * DM + k0 + seg * 4);
      ushort4 pk;
      pk.x = f2bf(v.x); pk.y = f2bf(v.y); pk.z = f2bf(v.z); pk.w = f2bf(v.w);
      *(ushort4*)(&Al[row * 40 + seg * 4]) = pk;
    }
#pragma unroll
    for (int i = 0; i < 2; ++i) {
      int idx = tid + i * 256;
      int row = idx >> 2, seg = idx & 3;
      *(int4*)(&Bl[row * 40 + seg * 8]) =
          *(const int4*)(Bt + (size_t)(n0 + row) * DM + k0 + seg * 8);
    }
    __syncthreads();
    bf16x8 af[4], bfr[4];
#pragma unroll
    for (int mi = 0; mi < 4; ++mi)
      af[mi] = *(const bf16x8*)(&Al[(wr * 64 + mi * 16 + l15) * 40 + g * 8]);
#pragma unroll
    for (int ni = 0; ni < 4; ++ni)
      bfr[ni] = *(const bf16x8*)(&Bl[(wc * 64 + ni * 16 + l15) * 40 + g * 8]);
#pragma unroll
    for (int mi = 0; mi < 4; ++mi)
#pragma unroll
      for (int ni = 0; ni < 4; ++ni)
        acc[mi][ni] = __builtin_amdgcn_mfma_f32_16x16x32_bf16(af[mi], bfr[ni], acc[mi][ni], 0, 0, 0);
    __syncthreads();
  }

  if (mode == 1) {
    // K fragment layout: kf[((bh*64 + kv>>5)*4 + d>>4)*64 + (kv&31) + ((d>>3)&1)*32][j=d&7]
#pragma unroll
    for (int mi = 0; mi < 4; ++mi) {
#pragma unroll
      for (int ni = 0; ni < 4; ++ni) {
        int n = n0 + wc * 64 + ni * 16 + l15;
        float bs = bias[n];
        int h = n >> 6, d = n & 63;
#pragma unroll
        for (int r = 0; r < 4; ++r) {
          int m = m0 + wr * 64 + mi * 16 + g * 4 + r;
          int b = m >> 11, kv = m & 2047;
          float val = acc[mi][ni][r] + bs;
          size_t addr = ((((size_t)(b * NH + h) * 64 + (kv >> 5)) * 4 + (d >> 4)) * 64 +
                         ((kv & 31) + ((d >> 3) & 1) * 32)) * 8 + (d & 7);
          kfo[addr] = f2bf(val);
        }
      }
    }
  } else {
    unsigned short* out = (mode == 0) ? qh : vh;
#pragma unroll
    for (int mi = 0; mi < 4; ++mi) {
#pragma unroll
      for (int ni = 0; ni < 4; ++ni) {
        int n = n0 + wc * 64 + ni * 16 + l15;
        float bs = bias[n];
        int h = n >> 6, d = n & 63;
#pragma unroll
        for (int r = 0; r < 4; ++r) {
          int m = m0 + wr * 64 + mi * 16 + g * 4 + r;
          int b = m >> 11, li = m & 2047;
          float val = (acc[mi][ni][r] + bs) * scale;
          out[(((size_t)(b * NH + h)) * LQ + li) * DK + d] = f2bf(val);
        }
      }
    }
  }
}

// ---------------------------------------------------------------------------
// Output GEMM: A[8192][512] bf16 @ Wo^T + bo -> f32
// ---------------------------------------------------------------------------
__global__ __launch_bounds__(256) void gemm_out(
    const unsigned short* __restrict__ A, const unsigned short* __restrict__ Bt,
    const float* __restrict__ bias, float* __restrict__ out)
{
  __shared__ __align__(16) unsigned short Al[128 * 40];
  __shared__ __align__(16) unsigned short Bl[128 * 40];
  const int tid = threadIdx.x;
  const int lane = tid & 63;
  const int w = tid >> 6;
  const int wr = w >> 1, wc = w & 1;
  const int l15 = lane & 15, g = lane >> 4;
  const int m0 = blockIdx.x * 128, n0 = blockIdx.y * 128;
  f32x4 acc[4][4] = {};

  for (int k0 = 0; k0 < DM; k0 += 32) {
#pragma unroll
    for (int i = 0; i < 2; ++i) {
      int idx = tid + i * 256;
      int row = idx >> 2, seg = idx & 3;
      *(int4*)(&Al[row * 40 + seg * 8]) =
          *(const int4*)(A + (size_t)(m0 + row) * DM + k0 + seg * 8);
      *(int4*)(&Bl[row * 40 + seg * 8]) =
          *(const int4*)(Bt + (size_t)(n0 + row) * DM + k0 + seg * 8);
    }
    __syncthreads();
    bf16x8 af[4], bfr[4];
#pragma unroll
    for (int mi = 0; mi < 4; ++mi)
      af[mi] = *(const bf16x8*)(&Al[(wr * 64 + mi * 16 + l15) * 40 + g * 8]);
#pragma unroll
    for (int ni = 0; ni < 4; ++ni)
      bfr[ni] = *(const bf16x8*)(&Bl[(wc * 64 + ni * 16 + l15) * 40 + g * 8]);
#pragma unroll
    for (int mi = 0; mi < 4; ++mi)
#pragma unroll
      for (int ni = 0; ni < 4; ++ni)
        acc[mi][ni] = __builtin_amdgcn_mfma_f32_16x16x32_bf16(af[mi], bfr[ni], acc[mi][ni], 0, 0, 0);
    __syncthreads();
  }

#pragma unroll
  for (int mi = 0; mi < 4; ++mi) {
#pragma unroll
    for (int ni = 0; ni < 4; ++ni) {
      int n = n0 + wc * 64 + ni * 16 + l15;
      float bs = bias[n];
#pragma unroll
      for (int r = 0; r < 4; ++r) {
        int m = m0 + wr * 64 + mi * 16 + g * 4 + r;
        out[(size_t)m * DM + n] = acc[mi][ni][r] + bs;
      }
    }
  }
}

// ---------------------------------------------------------------------------
// V transform with weight fold: vh[b,h,l,d] -> MFMA B-fragment layout
//   vf[((bh*128 + kv>>4)*2 + d>>5)*64 + (d&31) + ((kv>>3)&1)*32][j=kv&7]
//   element = w[kv] * V[kv][d]
// also emits wbf[b][l] = bf16(w[l]) (once per b, gated on h==0)
// ---------------------------------------------------------------------------
__global__ __launch_bounds__(256) void transpose_v(
    const unsigned short* __restrict__ vh, const float* __restrict__ wts,
    unsigned short* __restrict__ vf, unsigned short* __restrict__ wbf)
{
  __shared__ __align__(16) unsigned short t[64 * 72];
  const int bh = blockIdx.y, l0 = blockIdx.x * 64;
  const int b = bh >> 3;
  const size_t base = (size_t)bh * LKV * DK;
  const int tid = threadIdx.x;
  if ((bh & 7) == 0 && tid < 64)
    wbf[b * LKV + l0 + tid] = f2bf(wts[b * LKV + l0 + tid]);
#pragma unroll
  for (int i = 0; i < 2; ++i) {
    int idx = tid + i * 256;
    int row = idx >> 3, seg = idx & 7;
    *(int4*)(&t[row * 72 + seg * 8]) =
        *(const int4*)(vh + base + (size_t)(l0 + row) * DK + seg * 8);
  }
  __syncthreads();
#pragma unroll
  for (int i = 0; i < 2; ++i) {
    int idx = tid + i * 256;
    int d = idx >> 3, seg = idx & 7;
    int kvg = l0 + seg * 8;
    float4 wa = *(const float4*)(wts + b * LKV + kvg);
    float4 wb = *(const float4*)(wts + b * LKV + kvg + 4);
    unsigned short r0 = f2bf(wa.x * bf2f(t[(seg * 8 + 0) * 72 + d]));
    unsigned short r1 = f2bf(wa.y * bf2f(t[(seg * 8 + 1) * 72 + d]));
    unsigned short r2 = f2bf(wa.z * bf2f(t[(seg * 8 + 2) * 72 + d]));
    unsigned short r3 = f2bf(wa.w * bf2f(t[(seg * 8 + 3) * 72 + d]));
    unsigned short r4 = f2bf(wb.x * bf2f(t[(seg * 8 + 4) * 72 + d]));
    unsigned short r5 = f2bf(wb.y * bf2f(t[(seg * 8 + 5) * 72 + d]));
    unsigned short r6 = f2bf(wb.z * bf2f(t[(seg * 8 + 6) * 72 + d]));
    unsigned short r7 = f2bf(wb.w * bf2f(t[(seg * 8 + 7) * 72 + d]));
    int4 o;
    o.x = (int)((unsigned)r0 | ((unsigned)r1 << 16));
    o.y = (int)((unsigned)r2 | ((unsigned)r3 << 16));
    o.z = (int)((unsigned)r4 | ((unsigned)r5 << 16));
    o.w = (int)((unsigned)r6 | ((unsigned)r7 << 16));
    size_t addr = ((((size_t)bh * 128 + (kvg >> 4)) * 2 + (d >> 5)) * 64 +
                   ((d & 31) + ((kvg >> 3) & 1) * 32)) * 8;
    *(int4*)(vf + addr) = o;
  }
}

// ---------------------------------------------------------------------------
// Flash attention. 512-thread blocks = 8 waves = 4 q-groups x 2 kv-halves.
// Fragment-layout K/V in global -> lane-linear global_load_lds staging ->
// conflict-free linear ds_read_b128. 2-phase prefetch (stage t+1, compute t,
// one barrier per tile). kv-half partials combined in LDS (additive, no-max
// softmax). grid 512 = 32 bh (XCD-grouped) x 16 q-blocks of 128.
// ---------------------------------------------------------------------------
__global__ __launch_bounds__(512, 4) void attn_fwd(
    const unsigned short* __restrict__ qh, const unsigned short* __restrict__ kf,
    const unsigned short* __restrict__ vf, const unsigned short* __restrict__ wbf,
    unsigned short* __restrict__ ao)
{
  const int bid = blockIdx.x;
  const int xcd = bid & 7, wi = bid >> 3;   // 512 blocks, 64 per XCD
  const int bh = xcd * 4 + (wi >> 4);       // 4 bh per XCD (L2 locality)
  const int qb = wi & 15;
  const int b = bh >> 3, h = bh & 7;
  const int tid = threadIdx.x, lane = tid & 63, w = tid >> 6;
  const int wq = w & 3, half = w >> 2;
  const int l31 = lane & 31, hi = lane >> 5;

  // stage: [buf2][half2][K 4KB | V 4KB] = 32KB; combine aliases it after loop
  __shared__ __align__(16) char smem[35840];

  const size_t kv_bh = (size_t)bh * (LKV * DK);
  const unsigned short* kfb = kf + kv_bh;
  const unsigned short* vfb = vf + kv_bh;
  const unsigned short* wrow = wbf + b * LKV + half * 1024;

  const int q0 = qb * 128 + wq * 32;
  bf16x8 qf[4];
  {
    const unsigned short* qp = qh + kv_bh + (size_t)(q0 + l31) * DK + hi * 8;
#pragma unroll
    for (int cq = 0; cq < 4; ++cq) qf[cq] = *(const bf16x8*)(qp + cq * 16);
  }

  f32x16 accO0 = {}, accO1 = {}, accL = {};

#define STAGE(buf, t)                                                                     \
  do {                                                                                    \
    int tg_ = half * 32 + (t);                                                            \
    const unsigned short* ks_ = kfb + ((size_t)(tg_ * 4 + wq) * 64 + lane) * 8;           \
    const unsigned short* vs_ = vfb + ((size_t)((tg_ * 2 + (wq >> 1)) * 2 + (wq & 1)) * 64 + lane) * 8; \
    char* kd_ = smem + (buf) * 16384 + half * 8192 + wq * 1024;                           \
    char* vd_ = smem + (buf) * 16384 + half * 8192 + 4096 + wq * 1024;                    \
    __builtin_amdgcn_global_load_lds((const AS1 unsigned*)ks_, (AS3 unsigned*)kd_, 16, 0, 0); \
    __builtin_amdgcn_global_load_lds((const AS1 unsigned*)vs_, (AS3 unsigned*)vd_, 16, 0, 0); \
  } while (0)

  STAGE(0, 0);
  __syncthreads();

  int cur = 0;
#pragma unroll 2
  for (int t = 0; t < 32; ++t) {
    if (t < 31) STAGE(cur ^ 1, t + 1);

    const char* Kb = smem + cur * 16384 + half * 8192;
    const char* Vb = Kb + 4096;

    // ---- S^T = K.Q^T (32 kv x 32 q), lane: q = l31, kv per C-layout ----
    f32x16 s = {};
#pragma unroll
    for (int cq = 0; cq < 4; ++cq) {
      bf16x8 kfr = *(const bf16x8*)(Kb + cq * 1024 + lane * 16);
      s = __builtin_amdgcn_mfma_f32_32x32x16_bf16(kfr, qf[cq], s, 0, 0, 0);
    }

    // ---- u = exp2(S) (scale folded into qh), pack bf16 pairs ----
    unsigned D[8];
#pragma unroll
    for (int r2 = 0; r2 < 8; ++r2) {
      float lo = __builtin_amdgcn_exp2f(s[2 * r2]);
      float hv = __builtin_amdgcn_exp2f(s[2 * r2 + 1]);
      __bf16 bl = (__bf16)lo, bh2 = (__bf16)hv;
      unsigned short ul = __builtin_bit_cast(unsigned short, bl);
      unsigned short uh = __builtin_bit_cast(unsigned short, bh2);
      D[r2] = (unsigned)ul | ((unsigned)uh << 16);
    }

    const int kvt = t * 32;
    // ---- exchange to PV A-frag + MFMA PV and denominator ----
#pragma unroll
    for (int c = 0; c < 2; ++c) {
      int base = 4 * c;
      unsigned s0 = hi ? D[base] : D[base + 2];
      unsigned s1 = hi ? D[base + 1] : D[base + 3];
      unsigned X0 = (unsigned)__shfl_xor((int)s0, 32);
      unsigned X1 = (unsigned)__shfl_xor((int)s1, 32);
      union { unsigned u[4]; bf16x8 v; } pa;
      pa.u[0] = hi ? X0 : D[base];
      pa.u[1] = hi ? X1 : D[base + 1];
      pa.u[2] = hi ? D[base + 2] : X0;
      pa.u[3] = hi ? D[base + 3] : X1;

      bf16x8 vb0 = *(const bf16x8*)(Vb + (c * 2 + 0) * 1024 + lane * 16);
      bf16x8 vb1 = *(const bf16x8*)(Vb + (c * 2 + 1) * 1024 + lane * 16);
      bf16x8 wb = {};
      if (l31 == 0) wb = *(const bf16x8*)(wrow + kvt + c * 16 + hi * 8);

      accO0 = __builtin_amdgcn_mfma_f32_32x32x16_bf16(pa.v, vb0, accO0, 0, 0, 0);
      accO1 = __builtin_amdgcn_mfma_f32_32x32x16_bf16(pa.v, vb1, accO1, 0, 0, 0);
      accL  = __builtin_amdgcn_mfma_f32_32x32x16_bf16(pa.v, wb,  accL,  0, 0, 0);
    }
    __syncthreads();
    cur ^= 1;
  }
#undef STAGE

  // ---- combine kv-halves in LDS, normalize, store ----
  float* Ob = (float*)smem;                  // [4][32][68]
  float* Lb = (float*)(smem + 34816);        // [4][32]
  if (half == 1) {
#pragma unroll
    for (int r = 0; r < 16; ++r) {
      int qp_ = (r & 3) + 8 * (r >> 2) + 4 * hi;
      Ob[(wq * 32 + qp_) * 68 + l31] = accO0[r];
      Ob[(wq * 32 + qp_) * 68 + 32 + l31] = accO1[r];
    }
    if (l31 == 0) {
#pragma unroll
      for (int r = 0; r < 16; ++r) {
        int qp_ = (r & 3) + 8 * (r >> 2) + 4 * hi;
        Lb[wq * 32 + qp_] = accL[r];
      }
    }
  }
  __syncthreads();
  if (half == 0) {
#pragma unroll
    for (int r = 0; r < 16; ++r) {
      int qp_ = (r & 3) + 8 * (r >> 2) + 4 * hi;
      float L = __shfl(accL[r], lane & 32) + Lb[wq * 32 + qp_];
      float inv = 1.0f / L;
      float o0 = accO0[r] + Ob[(wq * 32 + qp_) * 68 + l31];
      float o1 = accO1[r] + Ob[(wq * 32 + qp_) * 68 + 32 + l31];
      size_t off = ((size_t)(b * LQ + q0 + qp_)) * DM + h * DK;
      ao[off + l31] = f2bf(o0 * inv);
      ao[off + 32 + l31] = f2bf(o1 * inv);
    }
  }
}

// ---------------------------------------------------------------------------
extern "C" void kernel_launch(void* const* d_in, const int* in_sizes, int n_in,
                              void* d_out, int out_size, void* d_ws, size_t ws_size,
                              hipStream_t stream)
{
  const float* q  = (const float*)d_in[0];
  const float* k  = (const float*)d_in[1];
  const float* v  = (const float*)d_in[2];
  const float* wt = (const float*)d_in[3];
  const float* Wq = (const float*)d_in[4];
  const float* bq = (const float*)d_in[5];
  const float* Wk = (const float*)d_in[6];
  const float* bk = (const float*)d_in[7];
  const float* Wv = (const float*)d_in[8];
  const float* bv = (const float*)d_in[9];
  const float* Wo = (const float*)d_in[10];
  const float* bo = (const float*)d_in[11];

  char* ws = (char*)d_ws;
  unsigned short* qh = (unsigned short*)(ws + 0);           //  8 MiB  [B,H,L,64] (scaled)
  unsigned short* kfr= (unsigned short*)(ws + 8388608);     //  8 MiB  K fragment layout
  unsigned short* vfr= (unsigned short*)(ws + 16777216);    //  8 MiB  V fragment layout (w-scaled)
  unsigned short* ao = (unsigned short*)(ws + 25165824);    //  8 MiB  [B,L,512]
  unsigned short* Wt = (unsigned short*)(ws + 33554432);    //  2 MiB  4x[512][512]
  unsigned short* vh = (unsigned short*)(ws + 35651584);    //  8 MiB  [B,H,L,64]
  unsigned short* wbf= (unsigned short*)(ws + 44040192);    // 16 KiB  [B,LKV] bf16 w

  transpose_w<<<dim3(16, 16, 4), 256, 0, stream>>>(Wq, Wk, Wv, Wo, Wt);
  gemm_qkv<<<dim3(64, 4, 3), 256, 0, stream>>>(q, k, v, Wt, bq, bk, bv, qh, kfr, vh);
  transpose_v<<<dim3(32, 32), 256, 0, stream>>>(vh, wt, vfr, wbf);
  attn_fwd<<<512, 512, 0, stream>>>(qh, kfr, vfr, wbf, ao);
  gemm_out<<<dim3(64, 4), 256, 0, stream>>>(ao, Wt + 3 * (size_t)DM * DM, bo, (float*)d_out);
}

// Round 5
// 110.719 us; speedup vs baseline: 1.8131x; 1.0215x over previous
//
#include <hip/hip_runtime.h>
#include <hip/hip_bf16.h>

#define LQ 2048
#define LKV 2048
#define DM 512
#define NH 8
#define DK 64

typedef __attribute__((ext_vector_type(8))) __bf16 bf16x8;
typedef __attribute__((ext_vector_type(4))) float f32x4;
typedef __attribute__((ext_vector_type(16))) float f32x16;

#define AS1 __attribute__((address_space(1)))
#define AS3 __attribute__((address_space(3)))

static __device__ __forceinline__ unsigned short f2bf(float x) {
  unsigned u = __float_as_uint(x);
  return (unsigned short)((u + 0x7fffu + ((u >> 16) & 1u)) >> 16);
}
static __device__ __forceinline__ float bf2f(unsigned short u) {
  return __uint_as_float(((unsigned)u) << 16);
}
static __device__ __forceinline__ bf16x8 cvt8(f32x4 a, f32x4 b) {
  bf16x8 r;
  r[0] = (__bf16)a[0]; r[1] = (__bf16)a[1]; r[2] = (__bf16)a[2]; r[3] = (__bf16)a[3];
  r[4] = (__bf16)b[0]; r[5] = (__bf16)b[1]; r[6] = (__bf16)b[2]; r[7] = (__bf16)b[3];
  return r;
}

// ---------------------------------------------------------------------------
// Transpose+convert W[512][512] f32 -> Wt[512][512] bf16 (Wt[n][k] = W[k][n])
// ---------------------------------------------------------------------------
__global__ __launch_bounds__(256) void transpose_w(
    const float* __restrict__ Wq, const float* __restrict__ Wk,
    const float* __restrict__ Wv, const float* __restrict__ Wo,
    unsigned short* __restrict__ WtAll)
{
  const float* W = blockIdx.z == 0 ? Wq : blockIdx.z == 1 ? Wk : blockIdx.z == 2 ? Wv : Wo;
  unsigned short* Wt = WtAll + (size_t)blockIdx.z * DM * DM;
  __shared__ float tile[32][33];
  const int t = threadIdx.x;
  const int tr = t >> 3;
  const int tc4 = (t & 7) * 4;
  const int k0 = blockIdx.x * 32, n0 = blockIdx.y * 32;
  float4 v = *(const float4*)(W + (size_t)(k0 + tr) * DM + n0 + tc4);
  tile[tr][tc4 + 0] = v.x; tile[tr][tc4 + 1] = v.y;
  tile[tr][tc4 + 2] = v.z; tile[tr][tc4 + 3] = v.w;
  __syncthreads();
  ushort4 o;
  o.x = f2bf(tile[tc4 + 0][tr]);
  o.y = f2bf(tile[tc4 + 1][tr]);
  o.z = f2bf(tile[tc4 + 2][tr]);
  o.w = f2bf(tile[tc4 + 3][tr]);
  *(ushort4*)(Wt + (size_t)(n0 + tr) * DM + k0 + tc4) = o;
}

// ---------------------------------------------------------------------------
// QKV projection GEMM v2. A f32 staged via global_load_lds with XOR-swizzled
// source (linear LDS dest), converted to bf16 AFTER the LDS fragment read.
// B (Wt bf16, row-major) staged via global_load_lds, fragment reads are
// conflict-free (64 B rows). XCD-bijective grid: all 4 n-tiles of one
// (mode,m-panel) on one XCD. grid 768 = 3 modes x 64 m x 4 n, block 256.
// Outputs: Q scaled by log2e/8 row-major head-major; K fragment layout; V row-major.
// ---------------------------------------------------------------------------
__global__ __launch_bounds__(256) void gemm_qkv(
    const float* __restrict__ qin, const float* __restrict__ kin, const float* __restrict__ vin,
    const unsigned short* __restrict__ WtAll,
    const float* __restrict__ bq, const float* __restrict__ bk, const float* __restrict__ bv,
    unsigned short* __restrict__ qh, unsigned short* __restrict__ kfo, unsigned short* __restrict__ vh)
{
  // bijective XCD grouping: panel p = mode*64+mtile lands on XCD p&7,
  // its 4 n-tiles are concurrent siblings on that XCD (A-panel L2 reuse).
  const int bid = blockIdx.x;
  const int x = bid & 7, j = bid >> 3;
  const int p = x + 8 * (j >> 2);
  const int nt = j & 3;
  const int mode = p >> 6, mtile = p & 63;

  const float* A = mode == 0 ? qin : (mode == 1 ? kin : vin);
  const unsigned short* Bt = WtAll + (size_t)mode * DM * DM;
  const float* bias = mode == 0 ? bq : (mode == 1 ? bk : bv);
  const float scale = (mode == 0) ? 0.18033688011112042f : 1.0f; // log2(e)/8

  __shared__ __align__(16) float As[128 * 32];           // 16 KB, swizzled slots
  __shared__ __align__(16) unsigned short Bs[128 * 32];  //  8 KB, row-major

  const int tid = threadIdx.x;
  const int lane = tid & 63;
  const int w = tid >> 6;
  const int wr = w >> 1, wc = w & 1;
  const int l15 = lane & 15, g = lane >> 4;
  const int m0 = mtile * 128, n0 = nt * 128;

  f32x4 acc[4][4] = {};

  for (int k0 = 0; k0 < DM; k0 += 32) {
    // stage A: 1024 16B chunks; LDS linear, source slot XOR-swizzled by row
#pragma unroll
    for (int i = 0; i < 4; ++i) {
      int c = tid + i * 256;
      int row = c >> 3, slot = c & 7;
      const float* src = A + (size_t)(m0 + row) * DM + k0 + ((slot ^ (row & 7)) << 2);
      __builtin_amdgcn_global_load_lds((const AS1 unsigned*)src,
                                       (AS3 unsigned*)((char*)As + c * 16), 16, 0, 0);
    }
    // stage B: 512 16B chunks, fully linear
#pragma unroll
    for (int i = 0; i < 2; ++i) {
      int c = tid + i * 256;
      int row = c >> 2, slot = c & 3;
      const unsigned short* src = Bt + (size_t)(n0 + row) * DM + k0 + slot * 8;
      __builtin_amdgcn_global_load_lds((const AS1 unsigned*)src,
                                       (AS3 unsigned*)((char*)Bs + c * 16), 16, 0, 0);
    }
    __syncthreads();

    bf16x8 af[4], bfr[4];
#pragma unroll
    for (int mi = 0; mi < 4; ++mi) {
      int row = wr * 64 + mi * 16 + l15;
      f32x4 a0 = *(const f32x4*)((const char*)As + row * 128 + (((2 * g) ^ (l15 & 7)) << 4));
      f32x4 a1 = *(const f32x4*)((const char*)As + row * 128 + (((2 * g + 1) ^ (l15 & 7)) << 4));
      af[mi] = cvt8(a0, a1);
    }
#pragma unroll
    for (int ni = 0; ni < 4; ++ni)
      bfr[ni] = *(const bf16x8*)((const char*)Bs + (wc * 64 + ni * 16 + l15) * 64 + g * 16);
#pragma unroll
    for (int mi = 0; mi < 4; ++mi)
#pragma unroll
      for (int ni = 0; ni < 4; ++ni)
        acc[mi][ni] = __builtin_amdgcn_mfma_f32_16x16x32_bf16(af[mi], bfr[ni], acc[mi][ni], 0, 0, 0);
    __syncthreads();
  }

  if (mode == 1) {
    // K fragment layout: kf[((bh*64 + kv>>5)*4 + d>>4)*64 + (kv&31) + ((d>>3)&1)*32][j=d&7]
#pragma unroll
    for (int mi = 0; mi < 4; ++mi) {
#pragma unroll
      for (int ni = 0; ni < 4; ++ni) {
        int n = n0 + wc * 64 + ni * 16 + l15;
        float bs = bias[n];
        int h = n >> 6, d = n & 63;
#pragma unroll
        for (int r = 0; r < 4; ++r) {
          int m = m0 + wr * 64 + mi * 16 + g * 4 + r;
          int b = m >> 11, kv = m & 2047;
          float val = acc[mi][ni][r] + bs;
          size_t addr = ((((size_t)(b * NH + h) * 64 + (kv >> 5)) * 4 + (d >> 4)) * 64 +
                         ((kv & 31) + ((d >> 3) & 1) * 32)) * 8 + (d & 7);
          kfo[addr] = f2bf(val);
        }
      }
    }
  } else {
    unsigned short* out = (mode == 0) ? qh : vh;
#pragma unroll
    for (int mi = 0; mi < 4; ++mi) {
#pragma unroll
      for (int ni = 0; ni < 4; ++ni) {
        int n = n0 + wc * 64 + ni * 16 + l15;
        float bs = bias[n];
        int h = n >> 6, d = n & 63;
#pragma unroll
        for (int r = 0; r < 4; ++r) {
          int m = m0 + wr * 64 + mi * 16 + g * 4 + r;
          int b = m >> 11, li = m & 2047;
          float val = (acc[mi][ni][r] + bs) * scale;
          out[(((size_t)(b * NH + h)) * LQ + li) * DK + d] = f2bf(val);
        }
      }
    }
  }
}

// ---------------------------------------------------------------------------
// Output GEMM: A[8192][512] bf16 @ Wo^T + bo -> f32
// ---------------------------------------------------------------------------
__global__ __launch_bounds__(256) void gemm_out(
    const unsigned short* __restrict__ A, const unsigned short* __restrict__ Bt,
    const float* __restrict__ bias, float* __restrict__ out)
{
  __shared__ __align__(16) unsigned short Al[128 * 40];
  __shared__ __align__(16) unsigned short Bl[128 * 40];
  const int tid = threadIdx.x;
  const int lane = tid & 63;
  const int w = tid >> 6;
  const int wr = w >> 1, wc = w & 1;
  const int l15 = lane & 15, g = lane >> 4;
  const int m0 = blockIdx.x * 128, n0 = blockIdx.y * 128;
  f32x4 acc[4][4] = {};

  for (int k0 = 0; k0 < DM; k0 += 32) {
#pragma unroll
    for (int i = 0; i < 2; ++i) {
      int idx = tid + i * 256;
      int row = idx >> 2, seg = idx & 3;
      *(int4*)(&Al[row * 40 + seg * 8]) =
          *(const int4*)(A + (size_t)(m0 + row) * DM + k0 + seg * 8);
      *(int4*)(&Bl[row * 40 + seg * 8]) =
          *(const int4*)(Bt + (size_t)(n0 + row) * DM + k0 + seg * 8);
    }
    __syncthreads();
    bf16x8 af[4], bfr[4];
#pragma unroll
    for (int mi = 0; mi < 4; ++mi)
      af[mi] = *(const bf16x8*)(&Al[(wr * 64 + mi * 16 + l15) * 40 + g * 8]);
#pragma unroll
    for (int ni = 0; ni < 4; ++ni)
      bfr[ni] = *(const bf16x8*)(&Bl[(wc * 64 + ni * 16 + l15) * 40 + g * 8]);
#pragma unroll
    for (int mi = 0; mi < 4; ++mi)
#pragma unroll
      for (int ni = 0; ni < 4; ++ni)
        acc[mi][ni] = __builtin_amdgcn_mfma_f32_16x16x32_bf16(af[mi], bfr[ni], acc[mi][ni], 0, 0, 0);
    __syncthreads();
  }

#pragma unroll
  for (int mi = 0; mi < 4; ++mi) {
#pragma unroll
    for (int ni = 0; ni < 4; ++ni) {
      int n = n0 + wc * 64 + ni * 16 + l15;
      float bs = bias[n];
#pragma unroll
      for (int r = 0; r < 4; ++r) {
        int m = m0 + wr * 64 + mi * 16 + g * 4 + r;
        out[(size_t)m * DM + n] = acc[mi][ni][r] + bs;
      }
    }
  }
}

// ---------------------------------------------------------------------------
// V transform with weight fold: vh[b,h,l,d] -> MFMA B-fragment layout
//   vf[((bh*128 + kv>>4)*2 + d>>5)*64 + (d&31) + ((kv>>3)&1)*32][j=kv&7]
//   element = w[kv] * V[kv][d]
// also emits wbf[b][l] = bf16(w[l]) (once per b, gated on h==0)
// ---------------------------------------------------------------------------
__global__ __launch_bounds__(256) void transpose_v(
    const unsigned short* __restrict__ vh, const float* __restrict__ wts,
    unsigned short* __restrict__ vf, unsigned short* __restrict__ wbf)
{
  __shared__ __align__(16) unsigned short t[64 * 72];
  const int bh = blockIdx.y, l0 = blockIdx.x * 64;
  const int b = bh >> 3;
  const size_t base = (size_t)bh * LKV * DK;
  const int tid = threadIdx.x;
  if ((bh & 7) == 0 && tid < 64)
    wbf[b * LKV + l0 + tid] = f2bf(wts[b * LKV + l0 + tid]);
#pragma unroll
  for (int i = 0; i < 2; ++i) {
    int idx = tid + i * 256;
    int row = idx >> 3, seg = idx & 7;
    *(int4*)(&t[row * 72 + seg * 8]) =
        *(const int4*)(vh + base + (size_t)(l0 + row) * DK + seg * 8);
  }
  __syncthreads();
#pragma unroll
  for (int i = 0; i < 2; ++i) {
    int idx = tid + i * 256;
    int d = idx >> 3, seg = idx & 7;
    int kvg = l0 + seg * 8;
    float4 wa = *(const float4*)(wts + b * LKV + kvg);
    float4 wb = *(const float4*)(wts + b * LKV + kvg + 4);
    unsigned short r0 = f2bf(wa.x * bf2f(t[(seg * 8 + 0) * 72 + d]));
    unsigned short r1 = f2bf(wa.y * bf2f(t[(seg * 8 + 1) * 72 + d]));
    unsigned short r2 = f2bf(wa.z * bf2f(t[(seg * 8 + 2) * 72 + d]));
    unsigned short r3 = f2bf(wa.w * bf2f(t[(seg * 8 + 3) * 72 + d]));
    unsigned short r4 = f2bf(wb.x * bf2f(t[(seg * 8 + 4) * 72 + d]));
    unsigned short r5 = f2bf(wb.y * bf2f(t[(seg * 8 + 5) * 72 + d]));
    unsigned short r6 = f2bf(wb.z * bf2f(t[(seg * 8 + 6) * 72 + d]));
    unsigned short r7 = f2bf(wb.w * bf2f(t[(seg * 8 + 7) * 72 + d]));
    int4 o;
    o.x = (int)((unsigned)r0 | ((unsigned)r1 << 16));
    o.y = (int)((unsigned)r2 | ((unsigned)r3 << 16));
    o.z = (int)((unsigned)r4 | ((unsigned)r5 << 16));
    o.w = (int)((unsigned)r6 | ((unsigned)r7 << 16));
    size_t addr = ((((size_t)bh * 128 + (kvg >> 4)) * 2 + (d >> 5)) * 64 +
                   ((d & 31) + ((kvg >> 3) & 1) * 32)) * 8;
    *(int4*)(vf + addr) = o;
  }
}

// ---------------------------------------------------------------------------
// Flash attention. 512-thread blocks = 8 waves = 4 q-groups x 2 kv-halves.
// Fragment-layout K/V in global -> lane-linear global_load_lds staging ->
// conflict-free linear ds_read_b128. 2-phase prefetch. kv-half partials
// combined in LDS (additive, no-max softmax). grid 512 = 32 bh x 16 q-blocks.
// ---------------------------------------------------------------------------
__global__ __launch_bounds__(512, 4) void attn_fwd(
    const unsigned short* __restrict__ qh, const unsigned short* __restrict__ kf,
    const unsigned short* __restrict__ vf, const unsigned short* __restrict__ wbf,
    unsigned short* __restrict__ ao)
{
  const int bid = blockIdx.x;
  const int xcd = bid & 7, wi = bid >> 3;   // 512 blocks, 64 per XCD
  const int bh = xcd * 4 + (wi >> 4);       // 4 bh per XCD (L2 locality)
  const int qb = wi & 15;
  const int b = bh >> 3, h = bh & 7;
  const int tid = threadIdx.x, lane = tid & 63, w = tid >> 6;
  const int wq = w & 3, half = w >> 2;
  const int l31 = lane & 31, hi = lane >> 5;

  __shared__ __align__(16) char smem[35840];

  const size_t kv_bh = (size_t)bh * (LKV * DK);
  const unsigned short* kfb = kf + kv_bh;
  const unsigned short* vfb = vf + kv_bh;
  const unsigned short* wrow = wbf + b * LKV + half * 1024;

  const int q0 = qb * 128 + wq * 32;
  bf16x8 qf[4];
  {
    const unsigned short* qp = qh + kv_bh + (size_t)(q0 + l31) * DK + hi * 8;
#pragma unroll
    for (int cq = 0; cq < 4; ++cq) qf[cq] = *(const bf16x8*)(qp + cq * 16);
  }

  f32x16 accO0 = {}, accO1 = {}, accL = {};

#define STAGE(buf, t)                                                                     \
  do {                                                                                    \
    int tg_ = half * 32 + (t);                                                            \
    const unsigned short* ks_ = kfb + ((size_t)(tg_ * 4 + wq) * 64 + lane) * 8;           \
    const unsigned short* vs_ = vfb + ((size_t)((tg_ * 2 + (wq >> 1)) * 2 + (wq & 1)) * 64 + lane) * 8; \
    char* kd_ = smem + (buf) * 16384 + half * 8192 + wq * 1024;                           \
    char* vd_ = smem + (buf) * 16384 + half * 8192 + 4096 + wq * 1024;                    \
    __builtin_amdgcn_global_load_lds((const AS1 unsigned*)ks_, (AS3 unsigned*)kd_, 16, 0, 0); \
    __builtin_amdgcn_global_load_lds((const AS1 unsigned*)vs_, (AS3 unsigned*)vd_, 16, 0, 0); \
  } while (0)

  STAGE(0, 0);
  __syncthreads();

  int cur = 0;
#pragma unroll 2
  for (int t = 0; t < 32; ++t) {
    if (t < 31) STAGE(cur ^ 1, t + 1);

    const char* Kb = smem + cur * 16384 + half * 8192;
    const char* Vb = Kb + 4096;

    f32x16 s = {};
#pragma unroll
    for (int cq = 0; cq < 4; ++cq) {
      bf16x8 kfr = *(const bf16x8*)(Kb + cq * 1024 + lane * 16);
      s = __builtin_amdgcn_mfma_f32_32x32x16_bf16(kfr, qf[cq], s, 0, 0, 0);
    }

    unsigned D[8];
#pragma unroll
    for (int r2 = 0; r2 < 8; ++r2) {
      float lo = __builtin_amdgcn_exp2f(s[2 * r2]);
      float hv = __builtin_amdgcn_exp2f(s[2 * r2 + 1]);
      __bf16 bl = (__bf16)lo, bh2 = (__bf16)hv;
      unsigned short ul = __builtin_bit_cast(unsigned short, bl);
      unsigned short uh = __builtin_bit_cast(unsigned short, bh2);
      D[r2] = (unsigned)ul | ((unsigned)uh << 16);
    }

    const int kvt = t * 32;
#pragma unroll
    for (int c = 0; c < 2; ++c) {
      int base = 4 * c;
      unsigned s0 = hi ? D[base] : D[base + 2];
      unsigned s1 = hi ? D[base + 1] : D[base + 3];
      unsigned X0 = (unsigned)__shfl_xor((int)s0, 32);
      unsigned X1 = (unsigned)__shfl_xor((int)s1, 32);
      union { unsigned u[4]; bf16x8 v; } pa;
      pa.u[0] = hi ? X0 : D[base];
      pa.u[1] = hi ? X1 : D[base + 1];
      pa.u[2] = hi ? D[base + 2] : X0;
      pa.u[3] = hi ? D[base + 3] : X1;

      bf16x8 vb0 = *(const bf16x8*)(Vb + (c * 2 + 0) * 1024 + lane * 16);
      bf16x8 vb1 = *(const bf16x8*)(Vb + (c * 2 + 1) * 1024 + lane * 16);
      bf16x8 wb = {};
      if (l31 == 0) wb = *(const bf16x8*)(wrow + kvt + c * 16 + hi * 8);

      accO0 = __builtin_amdgcn_mfma_f32_32x32x16_bf16(pa.v, vb0, accO0, 0, 0, 0);
      accO1 = __builtin_amdgcn_mfma_f32_32x32x16_bf16(pa.v, vb1, accO1, 0, 0, 0);
      accL  = __builtin_amdgcn_mfma_f32_32x32x16_bf16(pa.v, wb,  accL,  0, 0, 0);
    }
    __syncthreads();
    cur ^= 1;
  }
#undef STAGE

  float* Ob = (float*)smem;                  // [4][32][68]
  float* Lb = (float*)(smem + 34816);        // [4][32]
  if (half == 1) {
#pragma unroll
    for (int r = 0; r < 16; ++r) {
      int qp_ = (r & 3) + 8 * (r >> 2) + 4 * hi;
      Ob[(wq * 32 + qp_) * 68 + l31] = accO0[r];
      Ob[(wq * 32 + qp_) * 68 + 32 + l31] = accO1[r];
    }
    if (l31 == 0) {
#pragma unroll
      for (int r = 0; r < 16; ++r) {
        int qp_ = (r & 3) + 8 * (r >> 2) + 4 * hi;
        Lb[wq * 32 + qp_] = accL[r];
      }
    }
  }
  __syncthreads();
  if (half == 0) {
#pragma unroll
    for (int r = 0; r < 16; ++r) {
      int qp_ = (r & 3) + 8 * (r >> 2) + 4 * hi;
      float L = __shfl(accL[r], lane & 32) + Lb[wq * 32 + qp_];
      float inv = 1.0f / L;
      float o0 = accO0[r] + Ob[(wq * 32 + qp_) * 68 + l31];
      float o1 = accO1[r] + Ob[(wq * 32 + qp_) * 68 + 32 + l31];
      size_t off = ((size_t)(b * LQ + q0 + qp_)) * DM + h * DK;
      ao[off + l31] = f2bf(o0 * inv);
      ao[off + 32 + l31] = f2bf(o1 * inv);
    }
  }
}

// ---------------------------------------------------------------------------
extern "C" void kernel_launch(void* const* d_in, const int* in_sizes, int n_in,
                              void* d_out, int out_size, void* d_ws, size_t ws_size,
                              hipStream_t stream)
{
  const float* q  = (const float*)d_in[0];
  const float* k  = (const float*)d_in[1];
  const float* v  = (const float*)d_in[2];
  const float* wt = (const float*)d_in[3];
  const float* Wq = (const float*)d_in[4];
  const float* bq = (const float*)d_in[5];
  const float* Wk = (const float*)d_in[6];
  const float* bk = (const float*)d_in[7];
  const float* Wv = (const float*)d_in[8];
  const float* bv = (const float*)d_in[9];
  const float* Wo = (const float*)d_in[10];
  const float* bo = (const float*)d_in[11];

  char* ws = (char*)d_ws;
  unsigned short* qh = (unsigned short*)(ws + 0);           //  8 MiB  [B,H,L,64] (scaled)
  unsigned short* kfr= (unsigned short*)(ws + 8388608);     //  8 MiB  K fragment layout
  unsigned short* vfr= (unsigned short*)(ws + 16777216);    //  8 MiB  V fragment layout (w-scaled)
  unsigned short* ao = (unsigned short*)(ws + 25165824);    //  8 MiB  [B,L,512]
  unsigned short* Wt = (unsigned short*)(ws + 33554432);    //  2 MiB  4x[512][512]
  unsigned short* vh = (unsigned short*)(ws + 35651584);    //  8 MiB  [B,H,L,64]
  unsigned short* wbf= (unsigned short*)(ws + 44040192);    // 16 KiB  [B,LKV] bf16 w

  transpose_w<<<dim3(16, 16, 4), 256, 0, stream>>>(Wq, Wk, Wv, Wo, Wt);
  gemm_qkv<<<768, 256, 0, stream>>>(q, k, v, Wt, bq, bk, bv, qh, kfr, vh);
  transpose_v<<<dim3(32, 32), 256, 0, stream>>>(vh, wt, vfr, wbf);
  attn_fwd<<<512, 512, 0, stream>>>(qh, kfr, vfr, wbf, ao);
  gemm_out<<<dim3(64, 4), 256, 0, stream>>>(ao, Wt + 3 * (size_t)DM * DM, bo, (float*)d_out);
}

// Round 6
// 100.214 us; speedup vs baseline: 2.0032x; 1.1048x over previous
//
#include <hip/hip_runtime.h>
#include <hip/hip_bf16.h>

#define LQ 2048
#define LKV 2048
#define DM 512
#define NH 8
#define DK 64

typedef __attribute__((ext_vector_type(8))) __bf16 bf16x8;
typedef __attribute__((ext_vector_type(4))) float f32x4;
typedef __attribute__((ext_vector_type(16))) float f32x16;

#define AS1 __attribute__((address_space(1)))
#define AS3 __attribute__((address_space(3)))

static __device__ __forceinline__ unsigned short f2bf(float x) {
  unsigned u = __float_as_uint(x);
  return (unsigned short)((u + 0x7fffu + ((u >> 16) & 1u)) >> 16);
}
static __device__ __forceinline__ float bf2f(unsigned short u) {
  return __uint_as_float(((unsigned)u) << 16);
}
static __device__ __forceinline__ bf16x8 cvt8(f32x4 a, f32x4 b) {
  bf16x8 r;
  r[0] = (__bf16)a[0]; r[1] = (__bf16)a[1]; r[2] = (__bf16)a[2]; r[3] = (__bf16)a[3];
  r[4] = (__bf16)b[0]; r[5] = (__bf16)b[1]; r[6] = (__bf16)b[2]; r[7] = (__bf16)b[3];
  return r;
}

// ---------------------------------------------------------------------------
// Transpose+convert W[512][512] f32 -> Wt[512][512] bf16 (Wt[n][k] = W[k][n])
// ---------------------------------------------------------------------------
__global__ __launch_bounds__(256) void transpose_w(
    const float* __restrict__ Wq, const float* __restrict__ Wk,
    const float* __restrict__ Wv, const float* __restrict__ Wo,
    unsigned short* __restrict__ WtAll)
{
  const float* W = blockIdx.z == 0 ? Wq : blockIdx.z == 1 ? Wk : blockIdx.z == 2 ? Wv : Wo;
  unsigned short* Wt = WtAll + (size_t)blockIdx.z * DM * DM;
  __shared__ float tile[32][33];
  const int t = threadIdx.x;
  const int tr = t >> 3;
  const int tc4 = (t & 7) * 4;
  const int k0 = blockIdx.x * 32, n0 = blockIdx.y * 32;
  float4 v = *(const float4*)(W + (size_t)(k0 + tr) * DM + n0 + tc4);
  tile[tr][tc4 + 0] = v.x; tile[tr][tc4 + 1] = v.y;
  tile[tr][tc4 + 2] = v.z; tile[tr][tc4 + 3] = v.w;
  __syncthreads();
  ushort4 o;
  o.x = f2bf(tile[tc4 + 0][tr]);
  o.y = f2bf(tile[tc4 + 1][tr]);
  o.z = f2bf(tile[tc4 + 2][tr]);
  o.w = f2bf(tile[tc4 + 3][tr]);
  *(ushort4*)(Wt + (size_t)(n0 + tr) * DM + k0 + tc4) = o;
}

// ---------------------------------------------------------------------------
// QKV projection GEMM. A f32 staged via global_load_lds with XOR-swizzled
// source (linear LDS dest), converted to bf16 AFTER the LDS fragment read.
// B staged via global_load_lds with (row>>1)&3 slot swizzle (2-way reads).
// XCD-bijective grid: all 4 n-tiles of one (mode,m-panel) on one XCD.
// grid 768 = 3 modes x 64 m x 4 n, block 256.
// Outputs (ALL row-major head-major [B,H,L,64], coalescing 2B stores):
//   Q scaled by log2e/8, K, V.
// ---------------------------------------------------------------------------
__global__ __launch_bounds__(256) void gemm_qkv(
    const float* __restrict__ qin, const float* __restrict__ kin, const float* __restrict__ vin,
    const unsigned short* __restrict__ WtAll,
    const float* __restrict__ bq, const float* __restrict__ bk, const float* __restrict__ bv,
    unsigned short* __restrict__ qh, unsigned short* __restrict__ kh, unsigned short* __restrict__ vh)
{
  const int bid = blockIdx.x;
  const int x = bid & 7, j = bid >> 3;
  const int p = x + 8 * (j >> 2);
  const int nt = j & 3;
  const int mode = p >> 6, mtile = p & 63;

  const float* A = mode == 0 ? qin : (mode == 1 ? kin : vin);
  const unsigned short* Bt = WtAll + (size_t)mode * DM * DM;
  const float* bias = mode == 0 ? bq : (mode == 1 ? bk : bv);
  unsigned short* out = mode == 0 ? qh : (mode == 1 ? kh : vh);
  const float scale = (mode == 0) ? 0.18033688011112042f : 1.0f; // log2(e)/8

  __shared__ __align__(16) float As[128 * 32];           // 16 KB, swizzled slots
  __shared__ __align__(16) unsigned short Bs[128 * 32];  //  8 KB, swizzled slots

  const int tid = threadIdx.x;
  const int lane = tid & 63;
  const int w = tid >> 6;
  const int wr = w >> 1, wc = w & 1;
  const int l15 = lane & 15, g = lane >> 4;
  const int m0 = mtile * 128, n0 = nt * 128;

  f32x4 acc[4][4] = {};

  for (int k0 = 0; k0 < DM; k0 += 32) {
    // stage A: 1024 16B chunks; LDS linear, source slot XOR-swizzled by row
#pragma unroll
    for (int i = 0; i < 4; ++i) {
      int c = tid + i * 256;
      int row = c >> 3, slot = c & 7;
      const float* src = A + (size_t)(m0 + row) * DM + k0 + ((slot ^ (row & 7)) << 2);
      __builtin_amdgcn_global_load_lds((const AS1 unsigned*)src,
                                       (AS3 unsigned*)((char*)As + c * 16), 16, 0, 0);
    }
    // stage B: 512 16B chunks; slot swizzled by (row>>1)&3
#pragma unroll
    for (int i = 0; i < 2; ++i) {
      int c = tid + i * 256;
      int row = c >> 2, slot = c & 3;
      const unsigned short* src = Bt + (size_t)(n0 + row) * DM + k0 + ((slot ^ ((row >> 1) & 3)) * 8);
      __builtin_amdgcn_global_load_lds((const AS1 unsigned*)src,
                                       (AS3 unsigned*)((char*)Bs + c * 16), 16, 0, 0);
    }
    __syncthreads();

    bf16x8 af[4], bfr[4];
#pragma unroll
    for (int mi = 0; mi < 4; ++mi) {
      int row = wr * 64 + mi * 16 + l15;
      f32x4 a0 = *(const f32x4*)((const char*)As + row * 128 + (((2 * g) ^ (row & 7)) << 4));
      f32x4 a1 = *(const f32x4*)((const char*)As + row * 128 + (((2 * g + 1) ^ (row & 7)) << 4));
      af[mi] = cvt8(a0, a1);
    }
#pragma unroll
    for (int ni = 0; ni < 4; ++ni) {
      int row = wc * 64 + ni * 16 + l15;
      bfr[ni] = *(const bf16x8*)((const char*)Bs + row * 64 + ((g ^ ((row >> 1) & 3)) * 16));
    }
#pragma unroll
    for (int mi = 0; mi < 4; ++mi)
#pragma unroll
      for (int ni = 0; ni < 4; ++ni)
        acc[mi][ni] = __builtin_amdgcn_mfma_f32_16x16x32_bf16(af[mi], bfr[ni], acc[mi][ni], 0, 0, 0);
    __syncthreads();
  }

#pragma unroll
  for (int mi = 0; mi < 4; ++mi) {
#pragma unroll
    for (int ni = 0; ni < 4; ++ni) {
      int n = n0 + wc * 64 + ni * 16 + l15;
      float bs = bias[n];
      int h = n >> 6, d = n & 63;
#pragma unroll
      for (int r = 0; r < 4; ++r) {
        int m = m0 + wr * 64 + mi * 16 + g * 4 + r;
        int b = m >> 11, li = m & 2047;
        float val = (acc[mi][ni][r] + bs) * scale;
        out[(((size_t)(b * NH + h)) * LQ + li) * DK + d] = f2bf(val);
      }
    }
  }
}

// ---------------------------------------------------------------------------
// Output GEMM: A[8192][512] bf16 @ Wo^T + bo -> f32
// ---------------------------------------------------------------------------
__global__ __launch_bounds__(256) void gemm_out(
    const unsigned short* __restrict__ A, const unsigned short* __restrict__ Bt,
    const float* __restrict__ bias, float* __restrict__ out)
{
  __shared__ __align__(16) unsigned short Al[128 * 40];
  __shared__ __align__(16) unsigned short Bl[128 * 40];
  const int tid = threadIdx.x;
  const int lane = tid & 63;
  const int w = tid >> 6;
  const int wr = w >> 1, wc = w & 1;
  const int l15 = lane & 15, g = lane >> 4;
  const int m0 = blockIdx.x * 128, n0 = blockIdx.y * 128;
  f32x4 acc[4][4] = {};

  for (int k0 = 0; k0 < DM; k0 += 32) {
#pragma unroll
    for (int i = 0; i < 2; ++i) {
      int idx = tid + i * 256;
      int row = idx >> 2, seg = idx & 3;
      *(int4*)(&Al[row * 40 + seg * 8]) =
          *(const int4*)(A + (size_t)(m0 + row) * DM + k0 + seg * 8);
      *(int4*)(&Bl[row * 40 + seg * 8]) =
          *(const int4*)(Bt + (size_t)(n0 + row) * DM + k0 + seg * 8);
    }
    __syncthreads();
    bf16x8 af[4], bfr[4];
#pragma unroll
    for (int mi = 0; mi < 4; ++mi)
      af[mi] = *(const bf16x8*)(&Al[(wr * 64 + mi * 16 + l15) * 40 + g * 8]);
#pragma unroll
    for (int ni = 0; ni < 4; ++ni)
      bfr[ni] = *(const bf16x8*)(&Bl[(wc * 64 + ni * 16 + l15) * 40 + g * 8]);
#pragma unroll
    for (int mi = 0; mi < 4; ++mi)
#pragma unroll
      for (int ni = 0; ni < 4; ++ni)
        acc[mi][ni] = __builtin_amdgcn_mfma_f32_16x16x32_bf16(af[mi], bfr[ni], acc[mi][ni], 0, 0, 0);
    __syncthreads();
  }

#pragma unroll
  for (int mi = 0; mi < 4; ++mi) {
#pragma unroll
    for (int ni = 0; ni < 4; ++ni) {
      int n = n0 + wc * 64 + ni * 16 + l15;
      float bs = bias[n];
#pragma unroll
      for (int r = 0; r < 4; ++r) {
        int m = m0 + wr * 64 + mi * 16 + g * 4 + r;
        out[(size_t)m * DM + n] = acc[mi][ni][r] + bs;
      }
    }
  }
}

// ---------------------------------------------------------------------------
// prep_kv: (a) K row-major -> MFMA fragment layout. Pure 16B-block
// permutation (fragment d-chunks are contiguous): int4 in, int4 out.
//   kf[((bh*64 + kv>>5)*4 + cq)*64 + (kv&31) + hi*32][j] = K[kv][cq*16+hi*8+j]
// (b) V row-major -> w-folded B-fragment layout through LDS transpose.
// (c) wbf[b][l] = bf16(w[l]) (gated on h==0).
// grid (32, 32): x = 64-row tile, y = bh. block 256.
// ---------------------------------------------------------------------------
__global__ __launch_bounds__(256) void prep_kv(
    const unsigned short* __restrict__ kh, const unsigned short* __restrict__ vh,
    const float* __restrict__ wts,
    unsigned short* __restrict__ kf, unsigned short* __restrict__ vf,
    unsigned short* __restrict__ wbf)
{
  __shared__ __align__(16) unsigned short t[64 * 72];
  const int bh = blockIdx.y, l0 = blockIdx.x * 64;
  const int b = bh >> 3;
  const size_t base = (size_t)bh * LKV * DK;
  const int tid = threadIdx.x;

  if ((bh & 7) == 0 && tid < 64)
    wbf[b * LKV + l0 + tid] = f2bf(wts[b * LKV + l0 + tid]);

  // --- K permutation: 512 16B chunks, dst-linear ---
#pragma unroll
  for (int i = 0; i < 2; ++i) {
    int c = tid + i * 256;                       // 0..511
    int sl = c & 63, cq = (c >> 6) & 3, tl = c >> 8;
    int kv = tl * 32 + (sl & 31);
    int4 blk = *(const int4*)(kh + base + (size_t)(l0 + kv) * DK + cq * 16 + (sl >> 5) * 8);
    *(int4*)(kf + base + ((((size_t)(l0 >> 5) + tl) * 4 + cq) * 64 + sl) * 8) = blk;
  }

  // --- V transpose + weight fold ---
#pragma unroll
  for (int i = 0; i < 2; ++i) {
    int idx = tid + i * 256;
    int row = idx >> 3, seg = idx & 7;
    *(int4*)(&t[row * 72 + seg * 8]) =
        *(const int4*)(vh + base + (size_t)(l0 + row) * DK + seg * 8);
  }
  __syncthreads();
#pragma unroll
  for (int i = 0; i < 2; ++i) {
    int idx = tid + i * 256;
    int d = idx >> 3, seg = idx & 7;
    int kvg = l0 + seg * 8;
    float4 wa = *(const float4*)(wts + b * LKV + kvg);
    float4 wb = *(const float4*)(wts + b * LKV + kvg + 4);
    unsigned short r0 = f2bf(wa.x * bf2f(t[(seg * 8 + 0) * 72 + d]));
    unsigned short r1 = f2bf(wa.y * bf2f(t[(seg * 8 + 1) * 72 + d]));
    unsigned short r2 = f2bf(wa.z * bf2f(t[(seg * 8 + 2) * 72 + d]));
    unsigned short r3 = f2bf(wa.w * bf2f(t[(seg * 8 + 3) * 72 + d]));
    unsigned short r4 = f2bf(wb.x * bf2f(t[(seg * 8 + 4) * 72 + d]));
    unsigned short r5 = f2bf(wb.y * bf2f(t[(seg * 8 + 5) * 72 + d]));
    unsigned short r6 = f2bf(wb.z * bf2f(t[(seg * 8 + 6) * 72 + d]));
    unsigned short r7 = f2bf(wb.w * bf2f(t[(seg * 8 + 7) * 72 + d]));
    int4 o;
    o.x = (int)((unsigned)r0 | ((unsigned)r1 << 16));
    o.y = (int)((unsigned)r2 | ((unsigned)r3 << 16));
    o.z = (int)((unsigned)r4 | ((unsigned)r5 << 16));
    o.w = (int)((unsigned)r6 | ((unsigned)r7 << 16));
    size_t addr = ((((size_t)bh * 128 + (kvg >> 4)) * 2 + (d >> 5)) * 64 +
                   ((d & 31) + ((kvg >> 3) & 1) * 32)) * 8;
    *(int4*)(vf + addr) = o;
  }
}

// ---------------------------------------------------------------------------
// Flash attention. 512-thread blocks = 8 waves = 4 q-groups x 2 kv-halves.
// Fragment-layout K/V in global -> lane-linear global_load_lds staging ->
// conflict-free linear ds_read_b128. 2-phase prefetch. kv-half partials
// combined in LDS (additive, no-max softmax). grid 512 = 32 bh x 16 q-blocks.
// ---------------------------------------------------------------------------
__global__ __launch_bounds__(512, 4) void attn_fwd(
    const unsigned short* __restrict__ qh, const unsigned short* __restrict__ kf,
    const unsigned short* __restrict__ vf, const unsigned short* __restrict__ wbf,
    unsigned short* __restrict__ ao)
{
  const int bid = blockIdx.x;
  const int xcd = bid & 7, wi = bid >> 3;   // 512 blocks, 64 per XCD
  const int bh = xcd * 4 + (wi >> 4);       // 4 bh per XCD (L2 locality)
  const int qb = wi & 15;
  const int b = bh >> 3, h = bh & 7;
  const int tid = threadIdx.x, lane = tid & 63, w = tid >> 6;
  const int wq = w & 3, half = w >> 2;
  const int l31 = lane & 31, hi = lane >> 5;

  __shared__ __align__(16) char smem[35840];

  const size_t kv_bh = (size_t)bh * (LKV * DK);
  const unsigned short* kfb = kf + kv_bh;
  const unsigned short* vfb = vf + kv_bh;
  const unsigned short* wrow = wbf + b * LKV + half * 1024;

  const int q0 = qb * 128 + wq * 32;
  bf16x8 qf[4];
  {
    const unsigned short* qp = qh + kv_bh + (size_t)(q0 + l31) * DK + hi * 8;
#pragma unroll
    for (int cq = 0; cq < 4; ++cq) qf[cq] = *(const bf16x8*)(qp + cq * 16);
  }

  f32x16 accO0 = {}, accO1 = {}, accL = {};

#define STAGE(buf, t)                                                                     \
  do {                                                                                    \
    int tg_ = half * 32 + (t);                                                            \
    const unsigned short* ks_ = kfb + ((size_t)(tg_ * 4 + wq) * 64 + lane) * 8;           \
    const unsigned short* vs_ = vfb + ((size_t)((tg_ * 2 + (wq >> 1)) * 2 + (wq & 1)) * 64 + lane) * 8; \
    char* kd_ = smem + (buf) * 16384 + half * 8192 + wq * 1024;                           \
    char* vd_ = smem + (buf) * 16384 + half * 8192 + 4096 + wq * 1024;                    \
    __builtin_amdgcn_global_load_lds((const AS1 unsigned*)ks_, (AS3 unsigned*)kd_, 16, 0, 0); \
    __builtin_amdgcn_global_load_lds((const AS1 unsigned*)vs_, (AS3 unsigned*)vd_, 16, 0, 0); \
  } while (0)

  STAGE(0, 0);
  __syncthreads();

  int cur = 0;
#pragma unroll 2
  for (int t = 0; t < 32; ++t) {
    if (t < 31) STAGE(cur ^ 1, t + 1);

    const char* Kb = smem + cur * 16384 + half * 8192;
    const char* Vb = Kb + 4096;

    f32x16 s = {};
#pragma unroll
    for (int cq = 0; cq < 4; ++cq) {
      bf16x8 kfr = *(const bf16x8*)(Kb + cq * 1024 + lane * 16);
      s = __builtin_amdgcn_mfma_f32_32x32x16_bf16(kfr, qf[cq], s, 0, 0, 0);
    }

    unsigned D[8];
#pragma unroll
    for (int r2 = 0; r2 < 8; ++r2) {
      float lo = __builtin_amdgcn_exp2f(s[2 * r2]);
      float hv = __builtin_amdgcn_exp2f(s[2 * r2 + 1]);
      __bf16 bl = (__bf16)lo, bh2 = (__bf16)hv;
      unsigned short ul = __builtin_bit_cast(unsigned short, bl);
      unsigned short uh = __builtin_bit_cast(unsigned short, bh2);
      D[r2] = (unsigned)ul | ((unsigned)uh << 16);
    }

    const int kvt = t * 32;
#pragma unroll
    for (int c = 0; c < 2; ++c) {
      int base = 4 * c;
      unsigned s0 = hi ? D[base] : D[base + 2];
      unsigned s1 = hi ? D[base + 1] : D[base + 3];
      unsigned X0 = (unsigned)__shfl_xor((int)s0, 32);
      unsigned X1 = (unsigned)__shfl_xor((int)s1, 32);
      union { unsigned u[4]; bf16x8 v; } pa;
      pa.u[0] = hi ? X0 : D[base];
      pa.u[1] = hi ? X1 : D[base + 1];
      pa.u[2] = hi ? D[base + 2] : X0;
      pa.u[3] = hi ? D[base + 3] : X1;

      bf16x8 vb0 = *(const bf16x8*)(Vb + (c * 2 + 0) * 1024 + lane * 16);
      bf16x8 vb1 = *(const bf16x8*)(Vb + (c * 2 + 1) * 1024 + lane * 16);
      bf16x8 wb = {};
      if (l31 == 0) wb = *(const bf16x8*)(wrow + kvt + c * 16 + hi * 8);

      accO0 = __builtin_amdgcn_mfma_f32_32x32x16_bf16(pa.v, vb0, accO0, 0, 0, 0);
      accO1 = __builtin_amdgcn_mfma_f32_32x32x16_bf16(pa.v, vb1, accO1, 0, 0, 0);
      accL  = __builtin_amdgcn_mfma_f32_32x32x16_bf16(pa.v, wb,  accL,  0, 0, 0);
    }
    __syncthreads();
    cur ^= 1;
  }
#undef STAGE

  float* Ob = (float*)smem;                  // [4][32][68]
  float* Lb = (float*)(smem + 34816);        // [4][32]
  if (half == 1) {
#pragma unroll
    for (int r = 0; r < 16; ++r) {
      int qp_ = (r & 3) + 8 * (r >> 2) + 4 * hi;
      Ob[(wq * 32 + qp_) * 68 + l31] = accO0[r];
      Ob[(wq * 32 + qp_) * 68 + 32 + l31] = accO1[r];
    }
    if (l31 == 0) {
#pragma unroll
      for (int r = 0; r < 16; ++r) {
        int qp_ = (r & 3) + 8 * (r >> 2) + 4 * hi;
        Lb[wq * 32 + qp_] = accL[r];
      }
    }
  }
  __syncthreads();
  if (half == 0) {
#pragma unroll
    for (int r = 0; r < 16; ++r) {
      int qp_ = (r & 3) + 8 * (r >> 2) + 4 * hi;
      float L = __shfl(accL[r], lane & 32) + Lb[wq * 32 + qp_];
      float inv = 1.0f / L;
      float o0 = accO0[r] + Ob[(wq * 32 + qp_) * 68 + l31];
      float o1 = accO1[r] + Ob[(wq * 32 + qp_) * 68 + 32 + l31];
      size_t off = ((size_t)(b * LQ + q0 + qp_)) * DM + h * DK;
      ao[off + l31] = f2bf(o0 * inv);
      ao[off + 32 + l31] = f2bf(o1 * inv);
    }
  }
}

// ---------------------------------------------------------------------------
extern "C" void kernel_launch(void* const* d_in, const int* in_sizes, int n_in,
                              void* d_out, int out_size, void* d_ws, size_t ws_size,
                              hipStream_t stream)
{
  const float* q  = (const float*)d_in[0];
  const float* k  = (const float*)d_in[1];
  const float* v  = (const float*)d_in[2];
  const float* wt = (const float*)d_in[3];
  const float* Wq = (const float*)d_in[4];
  const float* bq = (const float*)d_in[5];
  const float* Wk = (const float*)d_in[6];
  const float* bk = (const float*)d_in[7];
  const float* Wv = (const float*)d_in[8];
  const float* bv = (const float*)d_in[9];
  const float* Wo = (const float*)d_in[10];
  const float* bo = (const float*)d_in[11];

  char* ws = (char*)d_ws;
  unsigned short* qh = (unsigned short*)(ws + 0);           //  8 MiB  [B,H,L,64] (scaled)
  unsigned short* kfr= (unsigned short*)(ws + 8388608);     //  8 MiB  K fragment layout
  unsigned short* vfr= (unsigned short*)(ws + 16777216);    //  8 MiB  V fragment layout (w-scaled)
  unsigned short* ao = (unsigned short*)(ws + 25165824);    //  8 MiB  [B,L,512]; doubles as kh
  unsigned short* Wt = (unsigned short*)(ws + 33554432);    //  2 MiB  4x[512][512]
  unsigned short* vh = (unsigned short*)(ws + 35651584);    //  8 MiB  [B,H,L,64]
  unsigned short* wbf= (unsigned short*)(ws + 44040192);    // 16 KiB  [B,LKV] bf16 w
  unsigned short* kh = ao;  // alias: consumed by prep_kv before attn writes ao

  transpose_w<<<dim3(16, 16, 4), 256, 0, stream>>>(Wq, Wk, Wv, Wo, Wt);
  gemm_qkv<<<768, 256, 0, stream>>>(q, k, v, Wt, bq, bk, bv, qh, kh, vh);
  prep_kv<<<dim3(32, 32), 256, 0, stream>>>(kh, vh, wt, kfr, vfr, wbf);
  attn_fwd<<<512, 512, 0, stream>>>(qh, kfr, vfr, wbf, ao);
  gemm_out<<<dim3(64, 4), 256, 0, stream>>>(ao, Wt + 3 * (size_t)DM * DM, bo, (float*)d_out);
}